// Round 11
// baseline (604.055 us; speedup 1.0000x reference)
//
#include <hip/hip_runtime.h>
#include <float.h>

// N=65536 vectors (16x4096), D=64, K=1024, all fp32.
// d_out (f32 flat concat): quantized[N*D], one-hot[N*K], loss, cb_loss, commit_loss.
//
// R11: pre-swizzled codebook fragments. R10's screen was 96% stall: b-frag
// loads had lanes striding 128 B -> 16 discontiguous cache lines per
// instruction. vq_prep now emits fbuf[tile][instr][lane][16B] (256 KB) in the
// exact per-lane MFMA consumption order, so every screen load is a contiguous
// 1 KB burst. Screen runs 1 wave/block (2 A-sets = 32 rows), grid 2048,
// no barriers, ~4-5 waves/SIMD for latency hiding.
// Certification unchanged: bf16-split MFMA (hh+hl+lh) err eps<=~5e-6; np-f32
// formula noise eta<=1.6e-5; screen gap >= BAND=6e-5 > 2*eta+2*eps proves the
// np argmin; else in-wave bit-exact np replica (R4-verified) re-scan.
#define NVEC 65536
#define KCB  1024
#define DIM  64
#define ENC_OFF   ((size_t)NVEC * DIM)
#define LOSS_OFF  (ENC_OFF + (size_t)NVEC * KCB)
#define BAND 6e-5f

// ws (bytes): se @64 (4KB); fbuf @8192 (256KB); idx(u16) @270336 (128KB)
#define WS_SE_BOFF   64
#define WS_FB_BOFF   8192
#define WS_IDX_BOFF  (8192 + 262144)

typedef __attribute__((ext_vector_type(8))) short short8;
typedef __attribute__((ext_vector_type(4))) float f32x4;

__device__ __forceinline__ unsigned short f2bf(float f) {
    unsigned u = __float_as_uint(f);
    return (unsigned short)((u + 0x7FFFu + ((u >> 16) & 1u)) >> 16);  // RNE
}
__device__ __forceinline__ float bf2f(unsigned short h) {
    return __uint_as_float((unsigned)h << 16);
}

// prep: loss zero, np-exact se[k], swizzled bf16 hi/lo fragment buffer.
// fbuf element (t,i,l,j), l=(q<<4)|c, k=t*16+c, d=(i&1)*32+q*8+j:
//   i<2 -> hi(emb[k][d]), i>=2 -> lo(emb[k][d]).
__global__ __launch_bounds__(256) void vq_prep(const float* __restrict__ emb,
                                               float* __restrict__ se,
                                               unsigned short* __restrict__ fbuf,
                                               float* __restrict__ loss3) {
    int g = blockIdx.x * 256 + threadIdx.x;  // 16384 threads
    if (g < 3) loss3[g] = 0.0f;
    if (g < KCB) {
        const f32x4* er = (const f32x4*)(emb + (size_t)g * DIM);
        double s0 = 0.0, s1 = 0.0, s2 = 0.0, s3 = 0.0;  // verbatim R4 chains
#pragma unroll
        for (int i = 0; i < 16; i++) {
            f32x4 e = er[i];
            s0 = fma((double)e.x, (double)e.x, s0);
            s1 = fma((double)e.y, (double)e.y, s1);
            s2 = fma((double)e.z, (double)e.z, s2);
            s3 = fma((double)e.w, (double)e.w, s3);
        }
        se[g] = (float)((s0 + s1) + (s2 + s3));
    }
    {
        int t = g >> 8, i = (g >> 6) & 3, l = g & 63;
        int c = l & 15, q = l >> 4;
        int k = t * 16 + c;
        int d0 = (i & 1) * 32 + q * 8;
        const float* src = emb + (size_t)k * DIM + d0;
        short8 v;
#pragma unroll
        for (int j = 0; j < 8; j++) {
            float f = src[j];
            unsigned short h = f2bf(f);
            v[j] = (i < 2) ? (short)h : (short)f2bf(f - bf2f(h));
        }
        *(short8*)(fbuf + (size_t)g * 8) = v;
    }
}

// Screen: 1 wave/block, 2 A-sets (32 rows), all K=1024. b-frags from fbuf:
// every load is 64 lanes x contiguous 16 B = 1 KB burst. Writes u16 idx only.
// MFMA 16x16x32 bf16 (layouts verified R7+): A[m=lane&15][k=quad*8+j],
// D col=lane&15 (code), rows=quad*4+reg.
__global__ __launch_bounds__(64, 4) void vq_screen(const float* __restrict__ x,
                                                   const float* __restrict__ emb,
                                                   const float* __restrict__ se,
                                                   const unsigned short* __restrict__ fbuf,
                                                   unsigned short* __restrict__ idxg) {
    __shared__ float sse[KCB];
    __shared__ int   sidx[32];
    __shared__ int   sflag[32];
    __shared__ int   scnt;
    __shared__ float sxrow[64];

    const int lane = threadIdx.x;
    const int q = lane >> 4, c = lane & 15;

    if (lane == 0) scnt = 0;
    for (int t = lane; t < KCB; t += 64) sse[t] = se[t];

    // A-frags for 2 sets: rows rowbase + s*16 + c
    const int rowbase = blockIdx.x * 32;
    short8 ah0[2], ah1[2], al0[2], al1[2];
#pragma unroll
    for (int s = 0; s < 2; s++) {
        float xa[16];
        const f32x4* xp = (const f32x4*)(x + (size_t)(rowbase + s * 16 + c) * DIM);
        ((f32x4*)xa)[0] = xp[2 * q];
        ((f32x4*)xa)[1] = xp[2 * q + 1];
        ((f32x4*)xa)[2] = xp[8 + 2 * q];
        ((f32x4*)xa)[3] = xp[8 + 2 * q + 1];
#pragma unroll
        for (int j = 0; j < 8; j++) {
            unsigned short h0 = f2bf(xa[j]);
            ah0[s][j] = (short)h0;
            al0[s][j] = (short)f2bf(xa[j] - bf2f(h0));
            unsigned short h1 = f2bf(xa[8 + j]);
            ah1[s][j] = (short)h1;
            al1[s][j] = (short)f2bf(xa[8 + j] - bf2f(h1));
        }
    }
    __syncthreads();  // sse, scnt

    float b1[2][4], b2[2][4];
    int i1[2][4];
#pragma unroll
    for (int s = 0; s < 2; s++)
#pragma unroll
        for (int r = 0; r < 4; r++) { b1[s][r] = FLT_MAX; b2[s][r] = FLT_MAX; i1[s][r] = 0; }

    const unsigned short* fb = fbuf + (size_t)lane * 8;  // + t*2048 + i*512
#pragma unroll 4
    for (int t = 0; t < 64; t++) {
        const unsigned short* fbt = fb + t * 2048;
        short8 bh0 = *(const short8*)(fbt);
        short8 bh1 = *(const short8*)(fbt + 512);
        short8 bl0 = *(const short8*)(fbt + 1024);
        short8 bl1 = *(const short8*)(fbt + 1536);
        int kcur = t * 16 + c;
        float sek = sse[kcur];
#pragma unroll
        for (int s = 0; s < 2; s++) {
            f32x4 acc = {0.f, 0.f, 0.f, 0.f};
            acc = __builtin_amdgcn_mfma_f32_16x16x32_bf16(ah0[s], bh0, acc, 0, 0, 0);
            acc = __builtin_amdgcn_mfma_f32_16x16x32_bf16(ah1[s], bh1, acc, 0, 0, 0);
            acc = __builtin_amdgcn_mfma_f32_16x16x32_bf16(ah0[s], bl0, acc, 0, 0, 0);
            acc = __builtin_amdgcn_mfma_f32_16x16x32_bf16(ah1[s], bl1, acc, 0, 0, 0);
            acc = __builtin_amdgcn_mfma_f32_16x16x32_bf16(al0[s], bh0, acc, 0, 0, 0);
            acc = __builtin_amdgcn_mfma_f32_16x16x32_bf16(al1[s], bh1, acc, 0, 0, 0);
#pragma unroll
            for (int r = 0; r < 4; r++) {
                float v = fmaf(-2.f, acc[r], sek);
                bool lt = v < b1[s][r];
                b2[s][r] = fminf(fmaxf(v, b1[s][r]), b2[s][r]);  // keep 2nd
                b1[s][r] = lt ? v : b1[s][r];
                i1[s][r] = lt ? kcur : i1[s][r];
            }
        }
    }

    // butterfly (b1,i1,b2) across the 16 lanes of each quad
#pragma unroll
    for (int m = 1; m <= 8; m <<= 1) {
#pragma unroll
        for (int s = 0; s < 2; s++)
#pragma unroll
            for (int r = 0; r < 4; r++) {
                float ob1 = __shfl_xor(b1[s][r], m, 64);
                float ob2 = __shfl_xor(b2[s][r], m, 64);
                int oi = __shfl_xor(i1[s][r], m, 64);
                float nb2 = fminf(fmaxf(b1[s][r], ob1), fminf(b2[s][r], ob2));
                if (ob1 < b1[s][r]) { b1[s][r] = ob1; i1[s][r] = oi; }
                b2[s][r] = nb2;
            }
    }
    if (c == 0) {
#pragma unroll
        for (int s = 0; s < 2; s++)
#pragma unroll
            for (int r = 0; r < 4; r++) {
                int row = s * 16 + q * 4 + r;  // D rows = quad*4+reg
                sidx[row] = i1[s][r];
                if (b2[s][r] - b1[s][r] < BAND) {
                    int p = atomicAdd(&scnt, 1);  // LDS atomic
                    sflag[p] = row;
                }
            }
    }
    __syncthreads();

    // in-wave refine of flagged rows (~0.8/block): bit-exact np replica (R4)
    int cnt = scnt;
    for (int f = 0; f < cnt; f++) {
        int row = sflag[f];
        int n = rowbase + row;
        if (lane < 16)
            ((f32x4*)sxrow)[lane] = ((const f32x4*)(x + (size_t)n * DIM))[lane];
        __syncthreads();  // single-wave barrier: publishes sxrow
        const float* xr = sxrow;

        float r8[8];
#pragma unroll
        for (int j = 0; j < 8; j++) r8[j] = 0.0f;
#pragma unroll
        for (int b = 0; b < 8; b++)
#pragma unroll
            for (int j = 0; j < 8; j++)
                r8[j] = __fadd_rn(r8[j], __fmul_rn(xr[8 * b + j], xr[8 * b + j]));
        float sx = __fadd_rn(
            __fadd_rn(__fadd_rn(r8[0], r8[1]), __fadd_rn(r8[2], r8[3])),
            __fadd_rn(__fadd_rn(r8[4], r8[5]), __fadd_rn(r8[6], r8[7])));

        float bd = FLT_MAX;
        int bk = lane * 16;
        for (int cc = 0; cc < 16; cc++) {
            int k = lane * 16 + cc;
            const f32x4* er = (const f32x4*)(emb + (size_t)k * DIM);
            double s0 = 0.0, s1 = 0.0, s2 = 0.0, s3 = 0.0;  // verbatim R4
#pragma unroll
            for (int i = 0; i < 16; i++) {
                f32x4 e = er[i];
                f32x4 xv = ((const f32x4*)xr)[i];
                s0 = fma((double)e.x, (double)xv.x, s0);
                s1 = fma((double)e.y, (double)xv.y, s1);
                s2 = fma((double)e.z, (double)xv.z, s2);
                s3 = fma((double)e.w, (double)xv.w, s3);
            }
            float dot32 = (float)((s0 + s1) + (s2 + s3));
            float t1 = __fadd_rn(sx, sse[k]);
            float d = __fsub_rn(t1, __fmul_rn(2.0f, dot32));
            if (d < bd) { bd = d; bk = k; }  // strict <
        }
        for (int off = 32; off; off >>= 1) {
            float od = __shfl_down(bd, off);
            int ok = __shfl_down(bk, off);
            if (od < bd || (od == bd && ok < bk)) { bd = od; bk = ok; }
        }
        if (lane == 0) sidx[row] = bk;
        __syncthreads();
    }

    if (lane < 32)
        idxg[rowbase + lane] = (unsigned short)sidx[lane];
}

// Writer: pure streaming output. block = 64 vectors (R10-proven).
__global__ __launch_bounds__(256) void vq_write(const float* __restrict__ x,
                                                const float* __restrict__ emb,
                                                const unsigned short* __restrict__ idxg,
                                                float* __restrict__ outq,
                                                float* __restrict__ enc,
                                                float* __restrict__ lossacc) {
    __shared__ int sidx[64];
    __shared__ float red[4];
    const int tid = threadIdx.x;
    if (tid < 64) sidx[tid] = idxg[blockIdx.x * 64 + tid];
    __syncthreads();

    {
        int vec = tid >> 2, ch = tid & 3;
        int id = sidx[vec];
        const f32x4* ebp = (const f32x4*)(emb + (size_t)id * DIM) + ch * 4;
        const f32x4* xp = (const f32x4*)(x + (size_t)(blockIdx.x * 64 + vec) * DIM) + ch * 4;
        f32x4* op = (f32x4*)(outq + (size_t)(blockIdx.x * 64 + vec) * DIM) + ch * 4;
        float sq = 0.0f;
#pragma unroll
        for (int i = 0; i < 4; i++) {
            f32x4 e = ebp[i];
            f32x4 xv = xp[i];
            f32x4 d = e - xv;
            sq += d.x * d.x + d.y * d.y + d.z * d.z + d.w * d.w;
            __builtin_nontemporal_store(e, op + i);
        }
        for (int off = 32; off; off >>= 1) sq += __shfl_down(sq, off);
        if ((tid & 63) == 0) red[tid >> 6] = sq;
        __syncthreads();
        if (tid == 0) atomicAdd(lossacc, red[0] + red[1] + red[2] + red[3]);
    }

    f32x4* encb = (f32x4*)enc + (size_t)blockIdx.x * 64 * 256;
    for (int t = tid; t < 64 * 256; t += 256) {
        int id = sidx[t >> 8];
        int j = (t & 255) << 2;
        f32x4 v;
        v.x = (id == j + 0) ? 1.0f : 0.0f;
        v.y = (id == j + 1) ? 1.0f : 0.0f;
        v.z = (id == j + 2) ? 1.0f : 0.0f;
        v.w = (id == j + 3) ? 1.0f : 0.0f;
        __builtin_nontemporal_store(v, encb + t);
    }
}

__global__ void vq_fin(float* __restrict__ loss3) {
    if (threadIdx.x == 0 && blockIdx.x == 0) {
        float m = loss3[1] * (1.0f / (float)((size_t)NVEC * DIM));
        loss3[0] = 1.25f * m;  // loss = cb + 0.25*commit (values identical)
        loss3[1] = m;
        loss3[2] = m;
    }
}

extern "C" void kernel_launch(void* const* d_in, const int* in_sizes, int n_in,
                              void* d_out, int out_size, void* d_ws, size_t ws_size,
                              hipStream_t stream) {
    const float* x = (const float*)d_in[0];
    const float* emb = (const float*)d_in[1];
    float* out = (float*)d_out;
    float* se = (float*)((char*)d_ws + WS_SE_BOFF);
    unsigned short* fbuf = (unsigned short*)((char*)d_ws + WS_FB_BOFF);
    unsigned short* idxg = (unsigned short*)((char*)d_ws + WS_IDX_BOFF);

    hipLaunchKernelGGL(vq_prep, dim3(64), dim3(256), 0, stream,
                       emb, se, fbuf, out + LOSS_OFF);
    hipLaunchKernelGGL(vq_screen, dim3(NVEC / 32), dim3(64), 0, stream,
                       x, emb, se, fbuf, idxg);
    hipLaunchKernelGGL(vq_write, dim3(NVEC / 64), dim3(256), 0, stream,
                       x, emb, idxg, out, out + ENC_OFF, out + LOSS_OFF + 1);
    hipLaunchKernelGGL(vq_fin, dim3(1), dim3(64), 0, stream, out + LOSS_OFF);
}

// Round 12
// 453.578 us; speedup vs baseline: 1.3318x; 1.3318x over previous
//
#include <hip/hip_runtime.h>
#include <float.h>

// N=65536 vectors (16x4096), D=64, K=1024, all fp32.
// d_out (f32 flat concat): quantized[N*D], one-hot[N*K], loss, cb_loss, commit_loss.
//
// R12 = R10's proven screen shape (256 thr, 4 waves x 2 A-sets, 512 blocks,
// no VGPR cap) + R11's swizzled fragment buffer as the ONLY change to the
// k-loop loads. R11's regression was a launch_bounds(64,4)-induced spill
// (VGPR 100->64, scratch WRITE 15.8 MB), not a failure of the swizzle.
//   vq_prep   : np-exact se[k]; fbuf[tile][instr][lane][16B] bf16 hi/lo
//   vq_screen : bf16-split MFMA argmin, (best,2nd) certification, in-block
//               bit-exact np refine, writes u16 idx only.
//   vq_write  : streaming one-hot + quantized + loss.
// Certification: eps(screen) <= ~5e-6, eta(np) <= 1.6e-5, BAND=6e-5 > 2eta+2eps.
#define NVEC 65536
#define KCB  1024
#define DIM  64
#define ENC_OFF   ((size_t)NVEC * DIM)
#define LOSS_OFF  (ENC_OFF + (size_t)NVEC * KCB)
#define BAND 6e-5f

// ws (bytes): se @64 (4KB); fbuf @8192 (256KB); idx(u16) @270336 (128KB)
#define WS_SE_BOFF   64
#define WS_FB_BOFF   8192
#define WS_IDX_BOFF  (8192 + 262144)

typedef __attribute__((ext_vector_type(8))) short short8;
typedef __attribute__((ext_vector_type(4))) float f32x4;

__device__ __forceinline__ unsigned short f2bf(float f) {
    unsigned u = __float_as_uint(f);
    return (unsigned short)((u + 0x7FFFu + ((u >> 16) & 1u)) >> 16);  // RNE
}
__device__ __forceinline__ float bf2f(unsigned short h) {
    return __uint_as_float((unsigned)h << 16);
}

// prep: loss zero, np-exact se[k], swizzled bf16 hi/lo fragment buffer.
// fbuf element (t,i,l,j), l=(q<<4)|c, k=t*16+c, d=(i&1)*32+q*8+j:
//   i<2 -> hi(emb[k][d]), i>=2 -> lo(emb[k][d]).
__global__ __launch_bounds__(256) void vq_prep(const float* __restrict__ emb,
                                               float* __restrict__ se,
                                               unsigned short* __restrict__ fbuf,
                                               float* __restrict__ loss3) {
    int g = blockIdx.x * 256 + threadIdx.x;  // 16384 threads
    if (g < 3) loss3[g] = 0.0f;
    if (g < KCB) {
        const f32x4* er = (const f32x4*)(emb + (size_t)g * DIM);
        double s0 = 0.0, s1 = 0.0, s2 = 0.0, s3 = 0.0;  // verbatim R4 chains
#pragma unroll
        for (int i = 0; i < 16; i++) {
            f32x4 e = er[i];
            s0 = fma((double)e.x, (double)e.x, s0);
            s1 = fma((double)e.y, (double)e.y, s1);
            s2 = fma((double)e.z, (double)e.z, s2);
            s3 = fma((double)e.w, (double)e.w, s3);
        }
        se[g] = (float)((s0 + s1) + (s2 + s3));
    }
    {
        int t = g >> 8, i = (g >> 6) & 3, l = g & 63;
        int c = l & 15, q = l >> 4;
        int k = t * 16 + c;
        int d0 = (i & 1) * 32 + q * 8;
        const float* src = emb + (size_t)k * DIM + d0;
        short8 v;
#pragma unroll
        for (int j = 0; j < 8; j++) {
            float f = src[j];
            unsigned short h = f2bf(f);
            v[j] = (i < 2) ? (short)h : (short)f2bf(f - bf2f(h));
        }
        *(short8*)(fbuf + (size_t)g * 8) = v;
    }
}

// Screen: block = 128 vectors (4 waves x 2 A-sets x 16 rows), 512 blocks.
// b-frags from fbuf: 64 lanes x contiguous 16 B = one 1 KB burst per load.
// MFMA 16x16x32 bf16 (layouts verified R7+): A[m=lane&15][k=quad*8+j],
// D col=lane&15 (code), rows=quad*4+reg.
__global__ __launch_bounds__(256) void vq_screen(const float* __restrict__ x,
                                                 const float* __restrict__ emb,
                                                 const float* __restrict__ se,
                                                 const unsigned short* __restrict__ fbuf,
                                                 unsigned short* __restrict__ idxg) {
    __shared__ float sse[KCB];
    __shared__ int   sidx[128];
    __shared__ int   sflag[128];
    __shared__ int   scnt;
    __shared__ float sxrow[4][64];

    const int tid = threadIdx.x;
    const int wave = tid >> 6, lane = tid & 63;
    const int q = lane >> 4, c = lane & 15;

    if (tid == 0) scnt = 0;
    for (int t = tid; t < KCB; t += 256) sse[t] = se[t];

    const int rowbase = blockIdx.x * 128 + wave * 32;
    short8 ah0[2], ah1[2], al0[2], al1[2];
#pragma unroll
    for (int s = 0; s < 2; s++) {
        float xa[16];
        const f32x4* xp = (const f32x4*)(x + (size_t)(rowbase + s * 16 + c) * DIM);
        ((f32x4*)xa)[0] = xp[2 * q];
        ((f32x4*)xa)[1] = xp[2 * q + 1];
        ((f32x4*)xa)[2] = xp[8 + 2 * q];
        ((f32x4*)xa)[3] = xp[8 + 2 * q + 1];
#pragma unroll
        for (int j = 0; j < 8; j++) {
            unsigned short h0 = f2bf(xa[j]);
            ah0[s][j] = (short)h0;
            al0[s][j] = (short)f2bf(xa[j] - bf2f(h0));
            unsigned short h1 = f2bf(xa[8 + j]);
            ah1[s][j] = (short)h1;
            al1[s][j] = (short)f2bf(xa[8 + j] - bf2f(h1));
        }
    }
    __syncthreads();  // sse + scnt ready

    float b1[2][4], b2[2][4];
    int i1[2][4];
#pragma unroll
    for (int s = 0; s < 2; s++)
#pragma unroll
        for (int r = 0; r < 4; r++) { b1[s][r] = FLT_MAX; b2[s][r] = FLT_MAX; i1[s][r] = 0; }

    // b-frag source: swizzled fragment buffer, lane-contiguous 16 B each.
    const unsigned short* fb = fbuf + (size_t)lane * 8;  // + t*2048 + i*512
#pragma unroll 4
    for (int t = 0; t < 64; t++) {
        const unsigned short* fbt = fb + t * 2048;
        short8 bh0 = *(const short8*)(fbt);
        short8 bh1 = *(const short8*)(fbt + 512);
        short8 bl0 = *(const short8*)(fbt + 1024);
        short8 bl1 = *(const short8*)(fbt + 1536);
        int kcur = t * 16 + c;
        float sek = sse[kcur];
#pragma unroll
        for (int s = 0; s < 2; s++) {
            f32x4 acc = {0.f, 0.f, 0.f, 0.f};
            acc = __builtin_amdgcn_mfma_f32_16x16x32_bf16(ah0[s], bh0, acc, 0, 0, 0);
            acc = __builtin_amdgcn_mfma_f32_16x16x32_bf16(ah1[s], bh1, acc, 0, 0, 0);
            acc = __builtin_amdgcn_mfma_f32_16x16x32_bf16(ah0[s], bl0, acc, 0, 0, 0);
            acc = __builtin_amdgcn_mfma_f32_16x16x32_bf16(ah1[s], bl1, acc, 0, 0, 0);
            acc = __builtin_amdgcn_mfma_f32_16x16x32_bf16(al0[s], bh0, acc, 0, 0, 0);
            acc = __builtin_amdgcn_mfma_f32_16x16x32_bf16(al1[s], bh1, acc, 0, 0, 0);
#pragma unroll
            for (int r = 0; r < 4; r++) {
                float v = fmaf(-2.f, acc[r], sek);
                bool lt = v < b1[s][r];
                b2[s][r] = fminf(fmaxf(v, b1[s][r]), b2[s][r]);  // keep 2nd
                b1[s][r] = lt ? v : b1[s][r];
                i1[s][r] = lt ? kcur : i1[s][r];
            }
        }
    }

    // butterfly (b1,i1,b2) across the 16 lanes of each quad
#pragma unroll
    for (int m = 1; m <= 8; m <<= 1) {
#pragma unroll
        for (int s = 0; s < 2; s++)
#pragma unroll
            for (int r = 0; r < 4; r++) {
                float ob1 = __shfl_xor(b1[s][r], m, 64);
                float ob2 = __shfl_xor(b2[s][r], m, 64);
                int oi = __shfl_xor(i1[s][r], m, 64);
                float nb2 = fminf(fmaxf(b1[s][r], ob1), fminf(b2[s][r], ob2));
                if (ob1 < b1[s][r]) { b1[s][r] = ob1; i1[s][r] = oi; }
                b2[s][r] = nb2;
            }
    }
    if (c == 0) {
#pragma unroll
        for (int s = 0; s < 2; s++)
#pragma unroll
            for (int r = 0; r < 4; r++) {
                int row = wave * 32 + s * 16 + q * 4 + r;  // D rows = quad*4+reg
                sidx[row] = i1[s][r];
                if (b2[s][r] - b1[s][r] < BAND) {
                    int p = atomicAdd(&scnt, 1);  // LDS atomic
                    sflag[p] = row;
                }
            }
    }
    __syncthreads();

    // in-block refine of flagged rows: verbatim R4 bit-exact np replica
    int cnt = scnt;
    for (int f = wave; f < cnt; f += 4) {
        int row = sflag[f];
        int n = blockIdx.x * 128 + row;
        if (lane < 16)
            ((f32x4*)sxrow[wave])[lane] = ((const f32x4*)(x + (size_t)n * DIM))[lane];
        const float* xr = sxrow[wave];

        float r8[8];
#pragma unroll
        for (int j = 0; j < 8; j++) r8[j] = 0.0f;
#pragma unroll
        for (int b = 0; b < 8; b++)
#pragma unroll
            for (int j = 0; j < 8; j++)
                r8[j] = __fadd_rn(r8[j], __fmul_rn(xr[8 * b + j], xr[8 * b + j]));
        float sx = __fadd_rn(
            __fadd_rn(__fadd_rn(r8[0], r8[1]), __fadd_rn(r8[2], r8[3])),
            __fadd_rn(__fadd_rn(r8[4], r8[5]), __fadd_rn(r8[6], r8[7])));

        float bd = FLT_MAX;
        int bk = lane * 16;
        for (int cc = 0; cc < 16; cc++) {
            int k = lane * 16 + cc;
            const f32x4* er = (const f32x4*)(emb + (size_t)k * DIM);
            double s0 = 0.0, s1 = 0.0, s2 = 0.0, s3 = 0.0;  // verbatim R4
#pragma unroll
            for (int i = 0; i < 16; i++) {
                f32x4 e = er[i];
                f32x4 xv = ((const f32x4*)xr)[i];
                s0 = fma((double)e.x, (double)xv.x, s0);
                s1 = fma((double)e.y, (double)xv.y, s1);
                s2 = fma((double)e.z, (double)xv.z, s2);
                s3 = fma((double)e.w, (double)xv.w, s3);
            }
            float dot32 = (float)((s0 + s1) + (s2 + s3));
            float t1 = __fadd_rn(sx, sse[k]);
            float d = __fsub_rn(t1, __fmul_rn(2.0f, dot32));
            if (d < bd) { bd = d; bk = k; }  // strict <
        }
        for (int off = 32; off; off >>= 1) {
            float od = __shfl_down(bd, off);
            int ok = __shfl_down(bk, off);
            if (od < bd || (od == bd && ok < bk)) { bd = od; bk = ok; }
        }
        if (lane == 0) sidx[row] = bk;
    }
    __syncthreads();

    if (tid < 128)
        idxg[blockIdx.x * 128 + tid] = (unsigned short)sidx[tid];
}

// Writer: pure streaming output. block = 64 vectors (R10-proven).
__global__ __launch_bounds__(256) void vq_write(const float* __restrict__ x,
                                                const float* __restrict__ emb,
                                                const unsigned short* __restrict__ idxg,
                                                float* __restrict__ outq,
                                                float* __restrict__ enc,
                                                float* __restrict__ lossacc) {
    __shared__ int sidx[64];
    __shared__ float red[4];
    const int tid = threadIdx.x;
    if (tid < 64) sidx[tid] = idxg[blockIdx.x * 64 + tid];
    __syncthreads();

    {
        int vec = tid >> 2, ch = tid & 3;
        int id = sidx[vec];
        const f32x4* ebp = (const f32x4*)(emb + (size_t)id * DIM) + ch * 4;
        const f32x4* xp = (const f32x4*)(x + (size_t)(blockIdx.x * 64 + vec) * DIM) + ch * 4;
        f32x4* op = (f32x4*)(outq + (size_t)(blockIdx.x * 64 + vec) * DIM) + ch * 4;
        float sq = 0.0f;
#pragma unroll
        for (int i = 0; i < 4; i++) {
            f32x4 e = ebp[i];
            f32x4 xv = xp[i];
            f32x4 d = e - xv;
            sq += d.x * d.x + d.y * d.y + d.z * d.z + d.w * d.w;
            __builtin_nontemporal_store(e, op + i);
        }
        for (int off = 32; off; off >>= 1) sq += __shfl_down(sq, off);
        if ((tid & 63) == 0) red[tid >> 6] = sq;
        __syncthreads();
        if (tid == 0) atomicAdd(lossacc, red[0] + red[1] + red[2] + red[3]);
    }

    f32x4* encb = (f32x4*)enc + (size_t)blockIdx.x * 64 * 256;
    for (int t = tid; t < 64 * 256; t += 256) {
        int id = sidx[t >> 8];
        int j = (t & 255) << 2;
        f32x4 v;
        v.x = (id == j + 0) ? 1.0f : 0.0f;
        v.y = (id == j + 1) ? 1.0f : 0.0f;
        v.z = (id == j + 2) ? 1.0f : 0.0f;
        v.w = (id == j + 3) ? 1.0f : 0.0f;
        __builtin_nontemporal_store(v, encb + t);
    }
}

__global__ void vq_fin(float* __restrict__ loss3) {
    if (threadIdx.x == 0 && blockIdx.x == 0) {
        float m = loss3[1] * (1.0f / (float)((size_t)NVEC * DIM));
        loss3[0] = 1.25f * m;  // loss = cb + 0.25*commit (values identical)
        loss3[1] = m;
        loss3[2] = m;
    }
}

extern "C" void kernel_launch(void* const* d_in, const int* in_sizes, int n_in,
                              void* d_out, int out_size, void* d_ws, size_t ws_size,
                              hipStream_t stream) {
    const float* x = (const float*)d_in[0];
    const float* emb = (const float*)d_in[1];
    float* out = (float*)d_out;
    float* se = (float*)((char*)d_ws + WS_SE_BOFF);
    unsigned short* fbuf = (unsigned short*)((char*)d_ws + WS_FB_BOFF);
    unsigned short* idxg = (unsigned short*)((char*)d_ws + WS_IDX_BOFF);

    hipLaunchKernelGGL(vq_prep, dim3(64), dim3(256), 0, stream,
                       emb, se, fbuf, out + LOSS_OFF);
    hipLaunchKernelGGL(vq_screen, dim3(NVEC / 128), dim3(256), 0, stream,
                       x, emb, se, fbuf, idxg);
    hipLaunchKernelGGL(vq_write, dim3(NVEC / 64), dim3(256), 0, stream,
                       x, emb, idxg, out, out + ENC_OFF, out + LOSS_OFF + 1);
    hipLaunchKernelGGL(vq_fin, dim3(1), dim3(64), 0, stream, out + LOSS_OFF);
}